// Round 5
// baseline (3440.768 us; speedup 1.0000x reference)
//
#include <hip/hip_runtime.h>
#include <hip/hip_bf16.h>

#define T_ 512
#define B_ 64
#define OBS_ 512
#define H_ 1024
#define A_ 18
#define MM_ (T_*B_)   // 32768
#define G4_ (4*H_)    // 4096
#define CH_ 64        // time steps per chunk
#define NCH_ (T_/CH_) // 8 chunks
#define CM_ (CH_*B_)  // 4096 rows per chunk

typedef unsigned short u16;
typedef unsigned long long u64;
typedef __attribute__((ext_vector_type(8))) short s8v;
typedef __attribute__((ext_vector_type(4))) float f4v;
typedef __attribute__((ext_vector_type(2))) u64 u64x2;

#define NAN16_PAT 0x7FC07FC07FC07FC0ULL
#define NAN32_PAT 0x7FC07FC0u

__device__ __forceinline__ float b2f(u16 u){
    unsigned x = ((unsigned)u) << 16;
    return __builtin_bit_cast(float, x);
}
__device__ __forceinline__ u16 f2b(float f){
    unsigned x = __builtin_bit_cast(unsigned, f);
    return (u16)((x + 0x7fffu + ((x >> 16) & 1u)) >> 16);  // RNE
}
// nonzero iff any 16-bit lane of x equals the bf16 NaN sentinel 0x7FC0
__device__ __forceinline__ u64 nan16(u64 x){
    u64 y = x ^ NAN16_PAT;
    return (y - 0x0001000100010001ULL) & ~y & 0x8000800080008000ULL;
}

// ---------------- small utility kernels ----------------

__global__ void cast_f32_bf16(const float* __restrict__ in, u16* __restrict__ out, int n){
    int i = blockIdx.x * blockDim.x + threadIdx.x;
    int stride = gridDim.x * blockDim.x;
    for (; i < n; i += stride) out[i] = f2b(in[i]);
}

__global__ void add_bias2(const float* __restrict__ a, const float* __restrict__ b,
                          float* __restrict__ out, int n){
    int i = blockIdx.x * blockDim.x + threadIdx.x;
    if (i < n) out[i] = a[i] + b[i];
}

// zero h_hist[0] + c; NaN-fill h_hist[1..CH_] (the data-flow sentinels)
__global__ void init_scan(u16* __restrict__ h_hist, float* __restrict__ c){
    int i = blockIdx.x * blockDim.x + threadIdx.x;
    int stride = gridDim.x * blockDim.x;
    unsigned* h0 = (unsigned*)h_hist;
    for (int k = i; k < B_*H_/2; k += stride) h0[k] = 0u;
    for (int k = i; k < B_*H_; k += stride) c[k] = 0.f;
    unsigned* p = (unsigned*)(h_hist + (size_t)B_*H_);
    for (int k = i; k < CH_*B_*H_/2; k += stride) p[k] = NAN32_PAT;
}

__global__ void copy_hc(const float* __restrict__ h, const float* __restrict__ c,
                        float* __restrict__ out){
    int i = blockIdx.x * blockDim.x + threadIdx.x;  // 65536 threads
    out[(size_t)MM_*A_ + i] = h[i];
    out[(size_t)MM_*A_ + B_*H_ + i] = c[i];
}

// ---------------- bf16 MFMA GEMM: C = act(A @ W^T + bias), W is (N,K) ----------------

#define LDSS 72  // 64 + 8 pad

template<bool A_FP32, bool RELU>
__global__ __launch_bounds__(256) void gemm_bt(
    const void* __restrict__ Aptr, const u16* __restrict__ W,
    const float* __restrict__ bias, u16* __restrict__ C,
    int M, int N, int K)
{
    __shared__ __align__(16) u16 As[128 * LDSS];
    __shared__ __align__(16) u16 Bs[128 * LDSS];

    const int tid  = threadIdx.x;
    const int lane = tid & 63;
    const int wid  = tid >> 6;
    const int wm   = wid & 1, wn = wid >> 1;
    const int m0   = blockIdx.y * 128, n0 = blockIdx.x * 128;
    const int quad = lane >> 4, l16 = lane & 15;

    f4v acc[4][4];
    #pragma unroll
    for (int i = 0; i < 4; i++)
        #pragma unroll
        for (int j = 0; j < 4; j++) acc[i][j] = (f4v){0.f,0.f,0.f,0.f};

    for (int k0 = 0; k0 < K; k0 += 64){
        __syncthreads();
        if (A_FP32){
            const float* A = (const float*)Aptr;
            #pragma unroll
            for (int pss = 0; pss < 8; pss++){
                int idx = pss * 256 + tid;
                int row = idx >> 4, ch = idx & 15;
                float4 v = *(const float4*)(A + (size_t)(m0 + row) * K + k0 + ch * 4);
                u16* d = &As[row * LDSS + ch * 4];
                d[0] = f2b(v.x); d[1] = f2b(v.y); d[2] = f2b(v.z); d[3] = f2b(v.w);
            }
        } else {
            const u16* A = (const u16*)Aptr;
            #pragma unroll
            for (int pss = 0; pss < 4; pss++){
                int idx = pss * 256 + tid;
                int row = idx >> 3, ch = idx & 7;
                *(uint4*)&As[row * LDSS + ch * 8] =
                    *(const uint4*)(A + (size_t)(m0 + row) * K + k0 + ch * 8);
            }
        }
        #pragma unroll
        for (int pss = 0; pss < 4; pss++){
            int idx = pss * 256 + tid;
            int row = idx >> 3, ch = idx & 7;
            *(uint4*)&Bs[row * LDSS + ch * 8] =
                *(const uint4*)(W + (size_t)(n0 + row) * K + k0 + ch * 8);
        }
        __syncthreads();

        #pragma unroll
        for (int kk = 0; kk < 64; kk += 32){
            s8v af[4], bf[4];
            #pragma unroll
            for (int mt = 0; mt < 4; mt++)
                af[mt] = *(const s8v*)&As[(wm*64 + mt*16 + l16) * LDSS + kk + quad*8];
            #pragma unroll
            for (int nt = 0; nt < 4; nt++)
                bf[nt] = *(const s8v*)&Bs[(wn*64 + nt*16 + l16) * LDSS + kk + quad*8];
            #pragma unroll
            for (int mt = 0; mt < 4; mt++)
                #pragma unroll
                for (int nt = 0; nt < 4; nt++)
                    acc[mt][nt] = __builtin_amdgcn_mfma_f32_16x16x32_bf16(
                        af[mt], bf[nt], acc[mt][nt], 0, 0, 0);
        }
    }

    #pragma unroll
    for (int mt = 0; mt < 4; mt++){
        #pragma unroll
        for (int nt = 0; nt < 4; nt++){
            #pragma unroll
            for (int r = 0; r < 4; r++){
                int m = m0 + wm*64 + mt*16 + quad*4 + r;
                int n = n0 + wn*64 + nt*16 + l16;
                float v = acc[mt][nt][r] + bias[n];
                if (RELU) v = fmaxf(v, 0.f);
                C[(size_t)m * N + n] = f2b(v);
            }
        }
    }
}

// ---------------- persistent LSTM scan, DATA-FLOW sync (no barrier, no counter) ----
// 256 blocks = 4 batch-groups (16 rows) x 64 N-slices (16 units). Whh slice in
// registers. h exchanged through rolling h_hist[st] seeded with bf16-NaN
// sentinels. Producers: packed-u32 agent-scope stores to LLC, fire-and-forget.
// Consumers: poll their own MFMA A-fragments with agent-scope u64 loads until
// NaN-free, then MFMA directly from the polled registers. Rendezvous latency =
// one LLC store flight + one poll sweep (vs round-4's drain+64-RMW+poll chain).

__global__ __launch_bounds__(256, 1) void lstm_scan(
    const u16* __restrict__ xg,      // [CH_][64][4096] chunk-local
    const u16* __restrict__ Whh,     // [4096][1024]
    u16* __restrict__ h_hist,        // [CH_+1][64][1024]; [0] = incoming h
    float* __restrict__ c_glob,      // [64][1024] fp32, persists across chunks
    float* __restrict__ h_f32,       // final-h staging (t == T-1 only)
    const float* __restrict__ mask,  // chunk-local
    int t0)
{
    __shared__ float red[4][4][16][16];  // [wave][gate][batch][unit] 16 KB

    const int tid  = threadIdx.x;
    const int lane = tid & 63;
    const int w    = tid >> 6;
    const int quad = lane >> 4, l16 = lane & 15;
    const int bid  = blockIdx.x;
    const int g = bid & 3;           // batch-group
    const int s = bid >> 2;          // N-slice
    const int rb0 = g * 16, j0 = s * 16;

    // Whh B-fragments, register-resident: B[n=lane&15][k=quad*8+j] [m89]
    const int koff = w * 256;
    s8v bf[4][8];
    #pragma unroll
    for (int gate = 0; gate < 4; gate++)
        #pragma unroll
        for (int ks = 0; ks < 8; ks++)
            bf[gate][ks] = *(const s8v*)(
                Whh + (size_t)(gate * H_ + j0 + l16) * H_ + koff + ks * 32 + quad * 8);

    const int cb = tid >> 4, cu = tid & 15;
    const size_t cidx = (size_t)(rb0 + cb) * H_ + j0 + cu;
    float c_reg = c_glob[cidx];

    // per-lane h-fragment base offset (u16 elements)
    const size_t hoff = (size_t)(rb0 + l16) * H_ + koff + quad * 8;

    for (int st = 0; st < CH_; st++){
        // ---- prefetch xg + mask (chunk-static, off the critical path)
        const u16* xgt = xg + (size_t)st * B_ * G4_ + (size_t)(rb0 + cb) * G4_ + j0 + cu;
        float xi = b2f(xgt[0]);
        float xf = b2f(xgt[H_]);
        float xv = b2f(xgt[2 * H_]);
        float xo = b2f(xgt[3 * H_]);
        float m  = mask[(size_t)st * B_ + rb0 + cb];

        // ---- data-poll h(st): 16 agent-scope u64 loads, NaN-sentinel check
        const u64* hp = (const u64*)(h_hist + (size_t)st * B_ * H_ + hoff);
        u64 v[16];
        int tries = 0;
        for (;;){
            #pragma unroll
            for (int ks = 0; ks < 8; ks++){
                v[2*ks]   = __hip_atomic_load(hp + ks*8,     __ATOMIC_RELAXED, __HIP_MEMORY_SCOPE_AGENT);
                v[2*ks+1] = __hip_atomic_load(hp + ks*8 + 1, __ATOMIC_RELAXED, __HIP_MEMORY_SCOPE_AGENT);
            }
            u64 bad = 0;
            #pragma unroll
            for (int i = 0; i < 16; i++) bad |= nan16(v[i]);
            if (!__any(bad != 0)) break;
            if (++tries > (1 << 22)) break;  // backstop: fail visibly, never hang
        }

        // ---- MFMA phase straight from polled registers
        f4v acc[4];
        #pragma unroll
        for (int gate = 0; gate < 4; gate++) acc[gate] = (f4v){0.f,0.f,0.f,0.f};
        #pragma unroll
        for (int ks = 0; ks < 8; ks++){
            u64x2 t = { v[2*ks], v[2*ks+1] };
            s8v af = __builtin_bit_cast(s8v, t);
            #pragma unroll
            for (int gate = 0; gate < 4; gate++)
                acc[gate] = __builtin_amdgcn_mfma_f32_16x16x32_bf16(af, bf[gate][ks], acc[gate], 0, 0, 0);
        }
        #pragma unroll
        for (int gate = 0; gate < 4; gate++)
            #pragma unroll
            for (int r = 0; r < 4; r++)
                red[w][gate][quad * 4 + r][l16] = acc[gate][r];
        __syncthreads();

        // ---- cell phase
        float gi = xi, gf = xf, gg = xv, go = xo;
        #pragma unroll
        for (int ww = 0; ww < 4; ww++){
            gi += red[ww][0][cb][cu];
            gf += red[ww][1][cb][cu];
            gg += red[ww][2][cb][cu];
            go += red[ww][3][cb][cu];
        }

        float is = 1.f / (1.f + __expf(-gi));
        float fs = 1.f / (1.f + __expf(-gf));
        float os = 1.f / (1.f + __expf(-go));
        float gt = tanhf(gg);

        float cn = fs * c_reg + is * gt;
        float hn = os * tanhf(cn);
        hn *= m; cn *= m;
        c_reg = cn;
        if (t0 + st == T_ - 1) h_f32[cidx] = hn;

        // ---- publish h(st+1): packed u32 LLC store, fire-and-forget
        unsigned hb = (unsigned)f2b(hn);
        unsigned partner = (unsigned)__shfl_xor((int)hb, 1, 64);
        if ((cu & 1) == 0){
            unsigned packed = hb | (partner << 16);
            unsigned* dst = (unsigned*)(h_hist + (size_t)(st + 1) * B_ * H_ + cidx);
            __hip_atomic_store(dst, packed, __ATOMIC_RELAXED, __HIP_MEMORY_SCOPE_AGENT);
            if (st == CH_ - 1){  // seed next chunk's h_hist[0]
                unsigned* dst0 = (unsigned*)(h_hist + cidx);
                __hip_atomic_store(dst0, packed, __ATOMIC_RELAXED, __HIP_MEMORY_SCOPE_AGENT);
            }
        }
        __syncthreads();  // protect red[] reuse across steps
    }

    c_glob[cidx] = c_reg;
}

// ---------------- decode + NaN-restore of consumed latent rows ----------------

__global__ __launch_bounds__(256) void decode_kernel(
    u16* __restrict__ latent, const u16* __restrict__ Wdec,
    const float* __restrict__ bdec, const float* __restrict__ mask,
    float* __restrict__ values, int rows)
{
    __shared__ __align__(16) u16 wl[A_ * H_];
    const int tid = threadIdx.x;
    for (int i = tid; i < A_ * H_ / 8; i += 256)
        ((uint4*)wl)[i] = ((const uint4*)Wdec)[i];
    __syncthreads();

    const int lane = tid & 63;
    int wid = blockIdx.x * 4 + (tid >> 6);
    const int nwaves = gridDim.x * 4;

    for (int row = wid; row < rows; row += nwaves){
        float lat[16];
        #pragma unroll
        for (int i = 0; i < 16; i++)
            lat[i] = b2f(latent[(size_t)row * H_ + i*64 + lane]);
        float acc[A_];
        #pragma unroll
        for (int a = 0; a < A_; a++) acc[a] = 0.f;
        #pragma unroll
        for (int i = 0; i < 16; i++){
            #pragma unroll
            for (int a = 0; a < A_; a++)
                acc[a] += lat[i] * b2f(wl[a * H_ + i*64 + lane]);
        }
        float m = mask[row];
        #pragma unroll
        for (int a = 0; a < A_; a++){
            float v = acc[a];
            #pragma unroll
            for (int s = 32; s > 0; s >>= 1) v += __shfl_down(v, s, 64);
            if (lane == 0) values[(size_t)row * A_ + a] = (v + bdec[a]) * m;
        }
        // restore NaN sentinels for the next chunk's data-flow sync
        unsigned* lrow = (unsigned*)(latent + (size_t)row * H_);
        #pragma unroll
        for (int i = 0; i < 8; i++) lrow[lane + i*64] = NAN32_PAT;
    }
}

// ---------------- launcher ----------------

extern "C" void kernel_launch(void* const* d_in, const int* in_sizes, int n_in,
                              void* d_out, int out_size, void* d_ws, size_t ws_size,
                              hipStream_t stream)
{
    const float* obs  = (const float*)d_in[0];
    const float* mask = (const float*)d_in[1];
    const float* Wenc = (const float*)d_in[2];
    const float* benc = (const float*)d_in[3];
    const float* Wih  = (const float*)d_in[4];
    const float* bih  = (const float*)d_in[5];
    const float* Whh  = (const float*)d_in[6];
    const float* bhh  = (const float*)d_in[7];
    const float* Wdec = (const float*)d_in[8];
    const float* bdec = (const float*)d_in[9];
    float* out = (float*)d_out;

    char* p = (char*)d_ws;
    size_t o = 0;
    auto alloc = [&](size_t bytes){ void* r = p + o; o += (bytes + 255) & ~(size_t)255; return r; };
    u16*      wenc_b  = (u16*)     alloc((size_t)H_ * OBS_ * 2);
    u16*      wih_b   = (u16*)     alloc((size_t)G4_ * H_ * 2);
    u16*      whh_b   = (u16*)     alloc((size_t)G4_ * H_ * 2);
    u16*      wdec_b  = (u16*)     alloc((size_t)A_ * H_ * 2);
    float*    bias2   = (float*)   alloc((size_t)G4_ * 4);
    u16*      enc_ch  = (u16*)     alloc((size_t)CM_ * H_ * 2);
    u16*      xg_ch   = (u16*)     alloc((size_t)CM_ * G4_ * 2);
    u16*      h_hist  = (u16*)     alloc((size_t)(CH_ + 1) * B_ * H_ * 2);  // 8.3 MB
    float*    h_f32   = (float*)   alloc((size_t)B_ * H_ * 4);
    float*    c_f32   = (float*)   alloc((size_t)B_ * H_ * 4);
    (void)ws_size; (void)in_sizes; (void)n_in; (void)out_size;

    cast_f32_bf16<<<1024, 256, 0, stream>>>(Wenc, wenc_b, H_ * OBS_);
    cast_f32_bf16<<<2048, 256, 0, stream>>>(Wih,  wih_b,  G4_ * H_);
    cast_f32_bf16<<<2048, 256, 0, stream>>>(Whh,  whh_b,  G4_ * H_);
    cast_f32_bf16<<<72,   256, 0, stream>>>(Wdec, wdec_b, A_ * H_);
    add_bias2<<<16, 256, 0, stream>>>(bih, bhh, bias2, G4_);
    init_scan<<<2048, 256, 0, stream>>>(h_hist, c_f32);

    for (int c = 0; c < NCH_; c++){
        const int t0 = c * CH_;

        dim3 g1(H_ / 128, CM_ / 128);
        gemm_bt<true, true><<<g1, 256, 0, stream>>>(
            obs + (size_t)t0 * B_ * OBS_, wenc_b, benc, enc_ch, CM_, H_, OBS_);

        dim3 g2(G4_ / 128, CM_ / 128);
        gemm_bt<false, false><<<g2, 256, 0, stream>>>(
            enc_ch, wih_b, bias2, xg_ch, CM_, G4_, H_);

        lstm_scan<<<256, 256, 0, stream>>>(
            xg_ch, whh_b, h_hist, c_f32, h_f32,
            mask + (size_t)t0 * B_, t0);

        // latent for this chunk == h_hist[1..CH_]; decode NaN-restores it
        decode_kernel<<<256, 256, 0, stream>>>(
            h_hist + (size_t)B_ * H_, wdec_b, bdec, mask + (size_t)t0 * B_,
            out + (size_t)t0 * B_ * A_, CM_);
    }

    copy_hc<<<256, 256, 0, stream>>>(h_f32, c_f32, out);
}

// Round 7
// 2756.934 us; speedup vs baseline: 1.2480x; 1.2480x over previous
//
#include <hip/hip_runtime.h>
#include <hip/hip_bf16.h>

#define T_ 512
#define B_ 64
#define OBS_ 512
#define H_ 1024
#define A_ 18
#define MM_ (T_*B_)   // 32768
#define G4_ (4*H_)    // 4096
#define CH_ 64        // time steps per chunk
#define NCH_ (T_/CH_) // 8 chunks
#define CM_ (CH_*B_)  // 4096 rows per chunk

typedef unsigned short u16;
typedef unsigned long long u64;
typedef __attribute__((ext_vector_type(8))) short s8v;
typedef __attribute__((ext_vector_type(4))) float f4v;

__device__ __forceinline__ float b2f(u16 u){
    unsigned x = ((unsigned)u) << 16;
    return __builtin_bit_cast(float, x);
}
__device__ __forceinline__ u16 f2b(float f){
    unsigned x = __builtin_bit_cast(unsigned, f);
    return (u16)((x + 0x7fffu + ((x >> 16) & 1u)) >> 16);  // RNE
}

// ---------------- small utility kernels ----------------

__global__ void cast_f32_bf16(const float* __restrict__ in, u16* __restrict__ out, int n){
    int i = blockIdx.x * blockDim.x + threadIdx.x;
    int stride = gridDim.x * blockDim.x;
    for (; i < n; i += stride) out[i] = f2b(in[i]);
}

__global__ void add_bias2(const float* __restrict__ a, const float* __restrict__ b,
                          float* __restrict__ out, int n){
    int i = blockIdx.x * blockDim.x + threadIdx.x;
    if (i < n) out[i] = a[i] + b[i];
}

// zero h_hist[0], c, and the 256 step-flags
__global__ void init_scan(u16* __restrict__ h_hist, float* __restrict__ c,
                          unsigned* __restrict__ flags){
    int i = blockIdx.x * blockDim.x + threadIdx.x;
    int stride = gridDim.x * blockDim.x;
    unsigned* h0 = (unsigned*)h_hist;
    for (int k = i; k < B_*H_/2; k += stride) h0[k] = 0u;
    for (int k = i; k < B_*H_; k += stride) c[k] = 0.f;
    if (i < 256) flags[i] = 0u;
}

__global__ void copy_hc(const float* __restrict__ h, const float* __restrict__ c,
                        float* __restrict__ out){
    int i = blockIdx.x * blockDim.x + threadIdx.x;  // 65536 threads
    out[(size_t)MM_*A_ + i] = h[i];
    out[(size_t)MM_*A_ + B_*H_ + i] = c[i];
}

// ---------------- bf16 MFMA GEMM: C = act(A @ W^T + bias), W is (N,K) ----------------

#define LDSS 72  // 64 + 8 pad

template<bool A_FP32, bool RELU>
__global__ __launch_bounds__(256) void gemm_bt(
    const void* __restrict__ Aptr, const u16* __restrict__ W,
    const float* __restrict__ bias, u16* __restrict__ C,
    int M, int N, int K)
{
    __shared__ __align__(16) u16 As[128 * LDSS];
    __shared__ __align__(16) u16 Bs[128 * LDSS];

    const int tid  = threadIdx.x;
    const int lane = tid & 63;
    const int wid  = tid >> 6;
    const int wm   = wid & 1, wn = wid >> 1;
    const int m0   = blockIdx.y * 128, n0 = blockIdx.x * 128;
    const int quad = lane >> 4, l16 = lane & 15;

    f4v acc[4][4];
    #pragma unroll
    for (int i = 0; i < 4; i++)
        #pragma unroll
        for (int j = 0; j < 4; j++) acc[i][j] = (f4v){0.f,0.f,0.f,0.f};

    for (int k0 = 0; k0 < K; k0 += 64){
        __syncthreads();
        if (A_FP32){
            const float* A = (const float*)Aptr;
            #pragma unroll
            for (int pss = 0; pss < 8; pss++){
                int idx = pss * 256 + tid;
                int row = idx >> 4, ch = idx & 15;
                float4 v = *(const float4*)(A + (size_t)(m0 + row) * K + k0 + ch * 4);
                u16* d = &As[row * LDSS + ch * 4];
                d[0] = f2b(v.x); d[1] = f2b(v.y); d[2] = f2b(v.z); d[3] = f2b(v.w);
            }
        } else {
            const u16* A = (const u16*)Aptr;
            #pragma unroll
            for (int pss = 0; pss < 4; pss++){
                int idx = pss * 256 + tid;
                int row = idx >> 3, ch = idx & 7;
                *(uint4*)&As[row * LDSS + ch * 8] =
                    *(const uint4*)(A + (size_t)(m0 + row) * K + k0 + ch * 8);
            }
        }
        #pragma unroll
        for (int pss = 0; pss < 4; pss++){
            int idx = pss * 256 + tid;
            int row = idx >> 3, ch = idx & 7;
            *(uint4*)&Bs[row * LDSS + ch * 8] =
                *(const uint4*)(W + (size_t)(n0 + row) * K + k0 + ch * 8);
        }
        __syncthreads();

        #pragma unroll
        for (int kk = 0; kk < 64; kk += 32){
            s8v af[4], bf[4];
            #pragma unroll
            for (int mt = 0; mt < 4; mt++)
                af[mt] = *(const s8v*)&As[(wm*64 + mt*16 + l16) * LDSS + kk + quad*8];
            #pragma unroll
            for (int nt = 0; nt < 4; nt++)
                bf[nt] = *(const s8v*)&Bs[(wn*64 + nt*16 + l16) * LDSS + kk + quad*8];
            #pragma unroll
            for (int mt = 0; mt < 4; mt++)
                #pragma unroll
                for (int nt = 0; nt < 4; nt++)
                    acc[mt][nt] = __builtin_amdgcn_mfma_f32_16x16x32_bf16(
                        af[mt], bf[nt], acc[mt][nt], 0, 0, 0);
        }
    }

    #pragma unroll
    for (int mt = 0; mt < 4; mt++){
        #pragma unroll
        for (int nt = 0; nt < 4; nt++){
            #pragma unroll
            for (int r = 0; r < 4; r++){
                int m = m0 + wm*64 + mt*16 + quad*4 + r;
                int n = n0 + wn*64 + nt*16 + l16;
                float v = acc[mt][nt][r] + bias[n];
                if (RELU) v = fmaxf(v, 0.f);
                C[(size_t)m * N + n] = f2b(v);
            }
        }
    }
}

// ---------------- persistent LSTM scan, per-slice FLAG rendezvous ----------------
// 256 blocks = 4 batch-groups (16 rows) x 64 N-slices (16 units). NO placement
// assumptions (round-6's XCD-claim scheme deadlocked; 256-block co-residency is
// proven by rounds 3-5). Rendezvous per step:
//   producer: h stores (sc1->LLC) -> per-wave vmcnt(0) -> syncthreads ->
//             tid0 stores flags[g][s] = t0+st+1 (plain sc1 store, single writer,
//             monotonic -- NO RMW serialization)
//   consumer: polls the 64 group flags (2x u64 agent loads/lane, 256 B/sweep --
//             no data-poll fabric congestion), then plain h loads (first touch
//             after gate => fresh from LLC; r4-validated pattern).
// xg/mask prefetched one step ahead AFTER the flag store, so HBM latency hides
// under the next rendezvous instead of becoming the group-wide straggler.

__global__ __launch_bounds__(256, 1) void lstm_scan(
    const u16* __restrict__ xg,      // [CH_][64][4096] chunk-local
    const u16* __restrict__ Whh,     // [4096][1024]
    u16* __restrict__ h_hist,        // [CH_+1][64][1024]; [0] = incoming h
    float* __restrict__ c_glob,      // [64][1024] fp32, persists across chunks
    float* __restrict__ h_f32,       // final-h staging (t == T-1 only)
    const float* __restrict__ mask,  // chunk-local
    unsigned* __restrict__ flags,    // [4][64] monotonic step flags
    int t0)
{
    __shared__ float red[4][4][16][17];  // [wave][gate][batch][unit(+pad)] ~17.4 KB

    const int tid  = threadIdx.x;
    const int lane = tid & 63;
    const int w    = tid >> 6;
    const int quad = lane >> 4, l16 = lane & 15;
    const int bid  = blockIdx.x;
    const int g = bid & 3, s = bid >> 2;
    const int rb0 = g * 16, j0 = s * 16;

    // Whh B-fragments: B[n=lane&15][k=quad*8+j] [m89]
    const int koff = w * 256;
    s8v bf[4][8];
    #pragma unroll
    for (int gate = 0; gate < 4; gate++)
        #pragma unroll
        for (int ks = 0; ks < 8; ks++)
            bf[gate][ks] = *(const s8v*)(
                Whh + (size_t)(gate * H_ + j0 + l16) * H_ + koff + ks * 32 + quad * 8);

    const int cb = tid >> 4, cu = tid & 15;
    const size_t cidx = (size_t)(rb0 + cb) * H_ + j0 + cu;
    float c_reg = c_glob[cidx];

    const size_t hoff = (size_t)(rb0 + l16) * H_ + koff + quad * 8;  // u16 elems
    unsigned* gflags = flags + (g << 6);
    const u64* fp = (const u64*)gflags + ((lane & 15) << 1);

    // prefetch xg + mask for st = 0
    const u16* xg0 = xg + (size_t)(rb0 + cb) * G4_ + j0 + cu;
    u16 nxi = xg0[0], nxf = xg0[H_], nxv = xg0[2 * H_], nxo = xg0[3 * H_];
    float nm = mask[rb0 + cb];

    for (int st = 0; st < CH_; st++){
        const float xi = b2f(nxi), xf = b2f(nxf), xv = b2f(nxv), xo = b2f(nxo);
        const float m = nm;

        // ---- flag poll: all 64 producers of this group have published h(st)
        const unsigned tgt = (unsigned)(t0 + st);
        int tries = 0;
        for (;;){
            u64 f0 = __hip_atomic_load(fp,     __ATOMIC_RELAXED, __HIP_MEMORY_SCOPE_AGENT);
            u64 f1 = __hip_atomic_load(fp + 1, __ATOMIC_RELAXED, __HIP_MEMORY_SCOPE_AGENT);
            bool ok = ((unsigned)f0 >= tgt) & ((unsigned)(f0 >> 32) >= tgt)
                    & ((unsigned)f1 >= tgt) & ((unsigned)(f1 >> 32) >= tgt);
            if (__all(ok)) break;
            if (++tries > (1 << 20)) break;  // backstop: fail visibly, never hang
        }

        // ---- h loads (fresh: first touch after gate) + MFMA
        const u16* hs = h_hist + (size_t)st * B_ * H_ + hoff;
        f4v acc[4];
        #pragma unroll
        for (int gate = 0; gate < 4; gate++) acc[gate] = (f4v){0.f,0.f,0.f,0.f};
        #pragma unroll
        for (int ks = 0; ks < 8; ks++){
            s8v af = *(const s8v*)(hs + ks * 32);
            #pragma unroll
            for (int gate = 0; gate < 4; gate++)
                acc[gate] = __builtin_amdgcn_mfma_f32_16x16x32_bf16(af, bf[gate][ks], acc[gate], 0, 0, 0);
        }
        #pragma unroll
        for (int gate = 0; gate < 4; gate++)
            #pragma unroll
            for (int r = 0; r < 4; r++)
                red[w][gate][quad * 4 + r][l16] = acc[gate][r];
        __syncthreads();

        // ---- cell phase
        float gi = xi, gf = xf, gg = xv, go = xo;
        #pragma unroll
        for (int ww = 0; ww < 4; ww++){
            gi += red[ww][0][cb][cu];
            gf += red[ww][1][cb][cu];
            gg += red[ww][2][cb][cu];
            go += red[ww][3][cb][cu];
        }

        float is = 1.f / (1.f + __expf(-gi));
        float fs = 1.f / (1.f + __expf(-gf));
        float os = 1.f / (1.f + __expf(-go));
        float gt = tanhf(gg);

        float cn = fs * c_reg + is * gt;
        float hn = os * tanhf(cn);
        hn *= m; cn *= m;
        c_reg = cn;
        if (t0 + st == T_ - 1) h_f32[cidx] = hn;

        // ---- publish h(st+1): packed u32 sc1 store to LLC
        unsigned hb = (unsigned)f2b(hn);
        unsigned partner = (unsigned)__shfl_xor((int)hb, 1, 64);
        if ((cu & 1) == 0){
            unsigned packed = hb | (partner << 16);
            unsigned* dst = (unsigned*)(h_hist + (size_t)(st + 1) * B_ * H_ + cidx);
            __hip_atomic_store(dst, packed, __ATOMIC_RELAXED, __HIP_MEMORY_SCOPE_AGENT);
            if (st == CH_ - 1){  // seed next chunk's h_hist[0]
                unsigned* dst0 = (unsigned*)(h_hist + cidx);
                __hip_atomic_store(dst0, packed, __ATOMIC_RELAXED, __HIP_MEMORY_SCOPE_AGENT);
            }
        }
        asm volatile("s_waitcnt vmcnt(0)" ::: "memory");  // this wave's h stores acked
        __syncthreads();                                   // all waves acked (also guards red[])

        // ---- release: single plain flag store (no RMW)
        if (tid == 0)
            __hip_atomic_store(gflags + s, (unsigned)(t0 + st + 1),
                               __ATOMIC_RELAXED, __HIP_MEMORY_SCOPE_AGENT);

        // ---- prefetch next step's xg/mask (after flag store: outside vmcnt window)
        if (st + 1 < CH_){
            const u16* xgn = xg + (size_t)(st + 1) * B_ * G4_ + (size_t)(rb0 + cb) * G4_ + j0 + cu;
            nxi = xgn[0]; nxf = xgn[H_]; nxv = xgn[2 * H_]; nxo = xgn[3 * H_];
            nm = mask[(size_t)(st + 1) * B_ + rb0 + cb];
        }
    }

    c_glob[cidx] = c_reg;
}

// ---------------- decode ----------------

__global__ __launch_bounds__(256) void decode_kernel(
    const u16* __restrict__ latent, const u16* __restrict__ Wdec,
    const float* __restrict__ bdec, const float* __restrict__ mask,
    float* __restrict__ values, int rows)
{
    __shared__ __align__(16) u16 wl[A_ * H_];
    const int tid = threadIdx.x;
    for (int i = tid; i < A_ * H_ / 8; i += 256)
        ((uint4*)wl)[i] = ((const uint4*)Wdec)[i];
    __syncthreads();

    const int lane = tid & 63;
    int wid = blockIdx.x * 4 + (tid >> 6);
    const int nwaves = gridDim.x * 4;

    for (int row = wid; row < rows; row += nwaves){
        float lat[16];
        #pragma unroll
        for (int i = 0; i < 16; i++)
            lat[i] = b2f(latent[(size_t)row * H_ + i*64 + lane]);
        float acc[A_];
        #pragma unroll
        for (int a = 0; a < A_; a++) acc[a] = 0.f;
        #pragma unroll
        for (int i = 0; i < 16; i++){
            #pragma unroll
            for (int a = 0; a < A_; a++)
                acc[a] += lat[i] * b2f(wl[a * H_ + i*64 + lane]);
        }
        float m = mask[row];
        #pragma unroll
        for (int a = 0; a < A_; a++){
            float v = acc[a];
            #pragma unroll
            for (int s = 32; s > 0; s >>= 1) v += __shfl_down(v, s, 64);
            if (lane == 0) values[(size_t)row * A_ + a] = (v + bdec[a]) * m;
        }
    }
}

// ---------------- launcher ----------------

extern "C" void kernel_launch(void* const* d_in, const int* in_sizes, int n_in,
                              void* d_out, int out_size, void* d_ws, size_t ws_size,
                              hipStream_t stream)
{
    const float* obs  = (const float*)d_in[0];
    const float* mask = (const float*)d_in[1];
    const float* Wenc = (const float*)d_in[2];
    const float* benc = (const float*)d_in[3];
    const float* Wih  = (const float*)d_in[4];
    const float* bih  = (const float*)d_in[5];
    const float* Whh  = (const float*)d_in[6];
    const float* bhh  = (const float*)d_in[7];
    const float* Wdec = (const float*)d_in[8];
    const float* bdec = (const float*)d_in[9];
    float* out = (float*)d_out;

    char* p = (char*)d_ws;
    size_t o = 0;
    auto alloc = [&](size_t bytes){ void* r = p + o; o += (bytes + 255) & ~(size_t)255; return r; };
    u16*      wenc_b  = (u16*)     alloc((size_t)H_ * OBS_ * 2);
    u16*      wih_b   = (u16*)     alloc((size_t)G4_ * H_ * 2);
    u16*      whh_b   = (u16*)     alloc((size_t)G4_ * H_ * 2);
    u16*      wdec_b  = (u16*)     alloc((size_t)A_ * H_ * 2);
    float*    bias2   = (float*)   alloc((size_t)G4_ * 4);
    u16*      enc_ch  = (u16*)     alloc((size_t)CM_ * H_ * 2);
    u16*      xg_ch   = (u16*)     alloc((size_t)CM_ * G4_ * 2);
    u16*      h_hist  = (u16*)     alloc((size_t)(CH_ + 1) * B_ * H_ * 2);  // 8.3 MB
    float*    h_f32   = (float*)   alloc((size_t)B_ * H_ * 4);
    float*    c_f32   = (float*)   alloc((size_t)B_ * H_ * 4);
    unsigned* flags   = (unsigned*)alloc(256 * 4);
    (void)ws_size; (void)in_sizes; (void)n_in; (void)out_size;

    cast_f32_bf16<<<1024, 256, 0, stream>>>(Wenc, wenc_b, H_ * OBS_);
    cast_f32_bf16<<<2048, 256, 0, stream>>>(Wih,  wih_b,  G4_ * H_);
    cast_f32_bf16<<<2048, 256, 0, stream>>>(Whh,  whh_b,  G4_ * H_);
    cast_f32_bf16<<<72,   256, 0, stream>>>(Wdec, wdec_b, A_ * H_);
    add_bias2<<<16, 256, 0, stream>>>(bih, bhh, bias2, G4_);
    init_scan<<<2048, 256, 0, stream>>>(h_hist, c_f32, flags);

    for (int c = 0; c < NCH_; c++){
        const int t0 = c * CH_;

        dim3 g1(H_ / 128, CM_ / 128);
        gemm_bt<true, true><<<g1, 256, 0, stream>>>(
            obs + (size_t)t0 * B_ * OBS_, wenc_b, benc, enc_ch, CM_, H_, OBS_);

        dim3 g2(G4_ / 128, CM_ / 128);
        gemm_bt<false, false><<<g2, 256, 0, stream>>>(
            enc_ch, wih_b, bias2, xg_ch, CM_, G4_, H_);

        lstm_scan<<<256, 256, 0, stream>>>(
            xg_ch, whh_b, h_hist, c_f32, h_f32,
            mask + (size_t)t0 * B_, flags, t0);

        // latent for this chunk == h_hist[1..CH_]
        decode_kernel<<<256, 256, 0, stream>>>(
            h_hist + (size_t)B_ * H_, wdec_b, bdec, mask + (size_t)t0 * B_,
            out + (size_t)t0 * B_ * A_, CM_);
    }

    copy_hc<<<256, 256, 0, stream>>>(h_f32, c_f32, out);
}